// Round 4
// baseline (260.178 us; speedup 1.0000x reference)
//
#include <hip/hip_runtime.h>
#include <math.h>

constexpr int BB = 2;
constexpr int SS = 2048;
constexpr int EE = 1024;
constexpr int HH = 16;
constexpr int DD = 64;

typedef short short8 __attribute__((ext_vector_type(8)));
typedef short short4_t __attribute__((ext_vector_type(4)));
typedef float floatx4 __attribute__((ext_vector_type(4)));
typedef unsigned short ushort_t;

__device__ __forceinline__ ushort_t f2bf(float f) {
    unsigned int u = __float_as_uint(f);
    u += 0x7fffu + ((u >> 16) & 1u);   // RNE
    return (ushort_t)(u >> 16);
}
__device__ __forceinline__ float bf2f(short s) {
    return __uint_as_float(((unsigned)(ushort_t)s) << 16);
}

// async global->LDS, 16 B per lane; LDS dest = uniform base + lane*16
__device__ __forceinline__ void gl_lds16(const void* g, void* l) {
    __builtin_amdgcn_global_load_lds(
        (const __attribute__((address_space(1))) void*)g,
        (__attribute__((address_space(3))) void*)l, 16, 0, 0);
}

// ---------------------------------------------------------------------------
// fp32 -> bf16 repack with XOR-group swizzle (phys group = g ^ (row&7) within
// each 64-col block). Handles all 3 X inputs and all 3 W matrices in one grid.
// ---------------------------------------------------------------------------
__global__ __launch_bounds__(256) void repack_all(
    const float* __restrict__ x0, const float* __restrict__ x1, const float* __restrict__ x2,
    const float* __restrict__ w0, const float* __restrict__ w1, const float* __restrict__ w2,
    ushort_t* __restrict__ Xbf, ushort_t* __restrict__ Wbf)
{
    const int idx = blockIdx.x * 256 + threadIdx.x;   // group-of-8 id
    const int row = idx >> 7;                          // 128 groups per row
    const int gir = idx & 127;
    const float* src;
    ushort_t* dst;
    int r;
    if (row < 3 * BB * SS) {
        const int z = row >> 12; r = row & (BB * SS - 1);
        src = (z == 0) ? x0 : (z == 1) ? x1 : x2;
        dst = Xbf + (size_t)z * BB * SS * EE;
    } else {
        const int rw = row - 3 * BB * SS;
        const int z = rw >> 10; r = rw & (EE - 1);
        src = (z == 0) ? w0 : (z == 1) ? w1 : w2;
        dst = Wbf + (size_t)z * EE * EE;
    }
    const int blk = gir >> 3, g = gir & 7;
    const int gp = g ^ (r & 7);
    const float* sp = src + (size_t)r * EE + gir * 8;
    float4 a = *(const float4*)sp;
    float4 b = *(const float4*)(sp + 4);
    short8 o;
    o[0] = (short)f2bf(a.x); o[1] = (short)f2bf(a.y); o[2] = (short)f2bf(a.z); o[3] = (short)f2bf(a.w);
    o[4] = (short)f2bf(b.x); o[5] = (short)f2bf(b.y); o[6] = (short)f2bf(b.z); o[7] = (short)f2bf(b.w);
    *(short8*)&dst[(size_t)r * EE + blk * 64 + gp * 8] = o;
}

// ---------------------------------------------------------------------------
// bf16 projection GEMM: 128x128 tile, BK=64, global_load_lds staging.
// z=0/1: q/k = X@W^T+b -> [bh][s][d] bf16 swizzled (d-groups XOR s&7)
// z=2:   vt           -> [bh][d][s] bf16 swizzled (s-groups XOR d&7)
// ---------------------------------------------------------------------------
__global__ __launch_bounds__(256) void proj_kernel(
    const ushort_t* __restrict__ Xall, const ushort_t* __restrict__ Wall,
    const float* __restrict__ bq, const float* __restrict__ bk, const float* __restrict__ bv,
    ushort_t* __restrict__ qb, ushort_t* __restrict__ kbb, ushort_t* __restrict__ vtb)
{
    __shared__ __align__(16) ushort_t Xs[128 * 64];
    __shared__ __align__(16) ushort_t Ws[128 * 64];

    const int z = blockIdx.z;
    const ushort_t* X = Xall + (size_t)z * BB * SS * EE;
    const ushort_t* W = Wall + (size_t)z * EE * EE;
    const float* bias = (z == 0) ? bq : (z == 1) ? bk : bv;

    const int t = threadIdx.x, w = t >> 6, l = t & 63, ln = t & 15, qd = (t >> 4) & 3;
    const int row0 = blockIdx.x * 128;
    const int col0 = blockIdx.y * 128;
    const int wzm = (w & 1) * 64, wzn = (w >> 1) * 64;

    floatx4 acc[4][4];
    #pragma unroll
    for (int i = 0; i < 4; ++i)
        #pragma unroll
        for (int j = 0; j < 4; ++j)
            acc[i][j] = (floatx4){0.f, 0.f, 0.f, 0.f};

    for (int k0 = 0; k0 < EE; k0 += 64) {
        __syncthreads();
        #pragma unroll
        for (int j = 0; j < 4; ++j) {
            const int c = w * 4 + j;
            const int r = c * 8 + (l >> 3);
            gl_lds16(&X[(size_t)(row0 + r) * EE + k0 + (l & 7) * 8], &Xs[c * 512]);
            gl_lds16(&W[(size_t)(col0 + r) * EE + k0 + (l & 7) * 8], &Ws[c * 512]);
        }
        __syncthreads();

        const ushort_t* Am = (z < 2) ? Ws : Xs;
        const ushort_t* Bn = (z < 2) ? Xs : Ws;
        #pragma unroll
        for (int kh = 0; kh < 2; ++kh) {
            const int sw = ((kh * 4 + qd) ^ (ln & 7)) * 8;
            short8 af[4], bfr[4];
            #pragma unroll
            for (int mi = 0; mi < 4; ++mi)
                af[mi] = *(const short8*)&Am[(wzm + mi * 16 + ln) * 64 + sw];
            #pragma unroll
            for (int ni = 0; ni < 4; ++ni)
                bfr[ni] = *(const short8*)&Bn[(wzn + ni * 16 + ln) * 64 + sw];
            #pragma unroll
            for (int mi = 0; mi < 4; ++mi)
                #pragma unroll
                for (int ni = 0; ni < 4; ++ni)
                    acc[mi][ni] = __builtin_amdgcn_mfma_f32_16x16x32_bf16(af[mi], bfr[ni], acc[mi][ni], 0, 0, 0);
        }
    }

    if (z < 2) {
        // m = o (4 consecutive outputs per reg-quad), n = s
        ushort_t* dst = z ? kbb : qb;
        #pragma unroll
        for (int mi = 0; mi < 4; ++mi) {
            const int o0 = col0 + wzm + mi * 16 + qd * 4;
            const float4 b4 = *(const float4*)&bias[o0];
            const int h = o0 >> 6, d0 = o0 & 63;
            const int g = d0 >> 3, dlow = d0 & 7;
            #pragma unroll
            for (int ni = 0; ni < 4; ++ni) {
                const int s = row0 + wzn + ni * 16 + ln;
                const int b = s >> 11, sr = s & (SS - 1);
                const int gp = g ^ (sr & 7);
                short4_t pk;
                pk[0] = (short)f2bf(acc[mi][ni][0] + b4.x);
                pk[1] = (short)f2bf(acc[mi][ni][1] + b4.y);
                pk[2] = (short)f2bf(acc[mi][ni][2] + b4.z);
                pk[3] = (short)f2bf(acc[mi][ni][3] + b4.w);
                *(short4_t*)&dst[((size_t)((b * HH + h) * SS) + sr) * DD + gp * 8 + dlow] = pk;
            }
        }
    } else {
        // m = s (4 consecutive per reg-quad), n = o ; vt[bh][d][s] swizzled
        #pragma unroll
        for (int mi = 0; mi < 4; ++mi) {
            const int s0 = row0 + wzm + mi * 16 + qd * 4;
            const int b = s0 >> 11, sr0 = s0 & (SS - 1);
            const int sg = (sr0 >> 3) & 7, slow = sr0 & 7;
            #pragma unroll
            for (int ni = 0; ni < 4; ++ni) {
                const int o = col0 + wzn + ni * 16 + ln;
                const int h = o >> 6, d = o & 63;
                const float bvv = bias[o];
                const int gp2 = sg ^ (d & 7);
                short4_t pk;
                pk[0] = (short)f2bf(acc[mi][ni][0] + bvv);
                pk[1] = (short)f2bf(acc[mi][ni][1] + bvv);
                pk[2] = (short)f2bf(acc[mi][ni][2] + bvv);
                pk[3] = (short)f2bf(acc[mi][ni][3] + bvv);
                *(short4_t*)&vtb[((size_t)((b * HH + h) * DD) + d) * SS + (sr0 & ~63) + gp2 * 8 + slow] = pk;
            }
        }
    }
}

// ---------------------------------------------------------------------------
// Suffix scan over S from bf16 vt[bh][d][s] (swizzled): 64-s chunk sums.
// ---------------------------------------------------------------------------
__global__ __launch_bounds__(256) void scan_chunks(
    const ushort_t* __restrict__ vtb, float* __restrict__ segs)
{
    const int t = threadIdx.x;
    const int d = blockIdx.x * 8 + (t >> 5);
    const int ch = t & 31;
    const int bh = blockIdx.y;
    const ushort_t* src = vtb + ((size_t)(bh * DD + d)) * SS + ch * 64;
    float s = 0.f;
    #pragma unroll
    for (int i = 0; i < 8; ++i) {
        short8 v = *(const short8*)&src[i * 8];
        #pragma unroll
        for (int j = 0; j < 8; ++j) s += bf2f(v[j]);   // swizzle permutes within 64-block: sum invariant
    }
    segs[((size_t)(bh * DD + d)) * 32 + ch] = s;
}

__global__ __launch_bounds__(256) void scan_finalize(
    const ushort_t* __restrict__ vtb, const float* __restrict__ segs,
    float* __restrict__ Sv, float* __restrict__ Tot)
{
    __shared__ float offp[4][64], subs[4][64];
    const int t = threadIdx.x, dd = t & 63, j = t >> 6;
    const int c = blockIdx.x, bh = blockIdx.y;

    float o = 0.f;
    for (int c2 = c + 1 + j; c2 < 32; c2 += 4)
        o += segs[((size_t)(bh * DD + dd)) * 32 + c2];
    offp[j][dd] = o;

    // logical s-range [j*16, j*16+16) -> physical groups (2j)^ (d&7), (2j+1)^(d&7)
    const ushort_t* vrow = vtb + ((size_t)(bh * DD + dd)) * SS + c * 64;
    const int g0 = (2 * j) ^ (dd & 7), g1 = (2 * j + 1) ^ (dd & 7);
    short8 a0 = *(const short8*)&vrow[g0 * 8];
    short8 a1 = *(const short8*)&vrow[g1 * 8];
    float arr[16];
    #pragma unroll
    for (int i = 0; i < 8; ++i) { arr[i] = bf2f(a0[i]); arr[8 + i] = bf2f(a1[i]); }
    float sub = 0.f;
    #pragma unroll
    for (int i = 0; i < 16; ++i) sub += arr[i];
    subs[j][dd] = sub;
    __syncthreads();

    float run = offp[0][dd] + offp[1][dd] + offp[2][dd] + offp[3][dd];
    for (int j2 = j + 1; j2 < 4; ++j2) run += subs[j2][dd];

    float* svp = Sv + ((size_t)bh * SS + c * 64 + j * 16) * DD + dd;
    for (int s = 15; s >= 0; --s) { svp[s * DD] = run; run += arr[s]; }
    if (c == 0 && j == 0) Tot[bh * DD + dd] = run;
}

// ---------------------------------------------------------------------------
// MFMA causal attention, log-softmax decomposition:
//   out[i,d] = sum_{k<=i} L[i,k] v[k,d] - lse_i*Tot[d] - 1e9*Sv[i,d]
// 512 threads = 8 waves x 16 rows; 64-wide K tiles, double-buffered async
// staging; P packed pairwise via DPP+v_perm -> ds_write2_b32, pitch-76 Ls.
// ---------------------------------------------------------------------------
__global__ __launch_bounds__(512, 4) void attn_kernel(
    const ushort_t* __restrict__ qb, const ushort_t* __restrict__ kbb,
    const ushort_t* __restrict__ vtb, const float* __restrict__ Sv,
    const float* __restrict__ Tot, const float* __restrict__ pb,
    float* __restrict__ out)
{
    __shared__ __align__(16) ushort_t Ks[2][64 * 64];   // [k][d], swizzled by k&7
    __shared__ __align__(16) ushort_t Vt[2][64 * 64];   // [d][k], swizzled by d&7
    __shared__ __align__(16) ushort_t Ls[128 * 76];     // [i][k] bf16, pitch 76
    __shared__ float pbL[2048];

    const int t = threadIdx.x, w = t >> 6, l = t & 63, ln = t & 15, qd = (t >> 4) & 3;
    const int id = blockIdx.x, bh = id & 31, tt = id >> 5;
    const int qt = (tt < 8) ? (15 - tt) : (tt - 8);   // heavy-first pairing
    const int b = bh >> 4, h = bh & 15, i0 = qt * 128;
    const int r0 = 16 * w;

    {   // pos_bias slice, rel in [0,2047]
        const float* p = pb + h * (2 * SS - 1) + (SS - 1);
        *(float4*)&pbL[t * 4] = *(const float4*)&p[t * 4];
    }

    // Q fragments (A-operand): row i0+r0+ln
    short8 qf[2];
    #pragma unroll
    for (int kh = 0; kh < 2; ++kh)
        qf[kh] = *(const short8*)&qb[((size_t)bh * SS + i0 + r0 + ln) * DD + (((kh * 4 + qd) ^ (ln & 7)) * 8)];

    floatx4 accpv[4];
    #pragma unroll
    for (int ct = 0; ct < 4; ++ct) accpv[ct] = (floatx4){0.f, 0.f, 0.f, 0.f};
    float part[4] = {};

    const int nkt = 2 * qt + 2;

    auto stage = [&](int buf, int kt) {
        const int k0 = kt * 64;
        const int row = w * 8 + (l >> 3), cg = l & 7;
        gl_lds16(&kbb[((size_t)bh * SS + k0 + row) * DD + cg * 8], &Ks[buf][w * 512]);
        gl_lds16(&vtb[((size_t)bh * DD + row) * SS + k0 + cg * 8], &Vt[buf][w * 512]);
    };

    stage(0, 0);
    for (int kt = 0; kt < nkt; ++kt) {
        __syncthreads();                                  // drains prefetch; buffers safe
        if (kt + 1 < nkt) stage((kt + 1) & 1, kt + 1);    // prefetch next tile
        const ushort_t* KsC = Ks[kt & 1];
        const ushort_t* VtC = Vt[kt & 1];
        const int k0 = kt * 64, kdiag = i0 - k0;

        if (kdiag + r0 + 15 < 0) continue;   // wave's rows fully masked this tile

        // QK^T
        floatx4 aq[4];
        #pragma unroll
        for (int ct = 0; ct < 4; ++ct) aq[ct] = (floatx4){0.f, 0.f, 0.f, 0.f};
        #pragma unroll
        for (int kh = 0; kh < 2; ++kh) {
            const int sw = ((kh * 4 + qd) ^ (ln & 7)) * 8;
            #pragma unroll
            for (int ct = 0; ct < 4; ++ct) {
                short8 bfr = *(const short8*)&KsC[(ct * 16 + ln) * 64 + sw];
                aq[ct] = __builtin_amdgcn_mfma_f32_16x16x32_bf16(qf[kh], bfr, aq[ct], 0, 0, 0);
            }
        }

        // scale + pos_bias (+ causal mask); exp accumulate; P -> Ls (paired b32)
        const int irel0 = r0 + qd * 4;
        unsigned* Ld = (unsigned*)Ls;
        const bool unmasked = (kt < 2 * qt);
        #pragma unroll
        for (int ct = 0; ct < 4; ++ct) {
            const int krel = ct * 16 + ln;
            const int pbase = kdiag + irel0 - krel;
            unsigned pk[4];
            #pragma unroll
            for (int reg = 0; reg < 4; ++reg) {
                unsigned u;
                if (unmasked) {
                    const float val = aq[ct][reg] * 0.125f + pbL[pbase + reg];
                    part[reg] += __expf(val);
                    u = __float_as_uint(val);
                } else {
                    const int rel = pbase + reg;
                    const bool ok = rel >= 0;
                    const float val = aq[ct][reg] * 0.125f + pbL[ok ? rel : 0];
                    part[reg] += ok ? __expf(val) : 0.f;
                    u = ok ? __float_as_uint(val) : 0u;
                }
                const unsigned nb = (unsigned)__builtin_amdgcn_mov_dpp((int)u, 0xF5, 0xF, 0xF, false);
                pk[reg] = __builtin_amdgcn_perm(nb, u, 0x07060302);  // [nb.hi16, u.hi16]
            }
            if (!(ln & 1)) {
                const int base = irel0 * 38 + (krel >> 1);   // dword index, pitch 38 dw
                Ld[base] = pk[0]; Ld[base + 38] = pk[1];
                Ld[base + 76] = pk[2]; Ld[base + 114] = pk[3];
            }
        }

        // PV (Ls rows wave-private: intra-wave DS ordering, no barrier)
        #pragma unroll
        for (int kh = 0; kh < 2; ++kh) {
            short8 af = *(const short8*)&Ls[(r0 + ln) * 76 + kh * 32 + qd * 8];
            const int sw = ((kh * 4 + qd) ^ (ln & 7)) * 8;
            #pragma unroll
            for (int ct = 0; ct < 4; ++ct) {
                short8 bfr = *(const short8*)&VtC[(ct * 16 + ln) * 64 + sw];
                accpv[ct] = __builtin_amdgcn_mfma_f32_16x16x32_bf16(af, bfr, accpv[ct], 0, 0, 0);
            }
        }
    }

    // row lse via 16-lane shuffle reduction
    float lse[4];
    #pragma unroll
    for (int reg = 0; reg < 4; ++reg) {
        float p = part[reg];
        p += __shfl_xor(p, 1, 64);
        p += __shfl_xor(p, 2, 64);
        p += __shfl_xor(p, 4, 64);
        p += __shfl_xor(p, 8, 64);
        lse[reg] = __logf(p);
    }

    float tot[4];
    #pragma unroll
    for (int ct = 0; ct < 4; ++ct) tot[ct] = Tot[bh * DD + ct * 16 + ln];

    #pragma unroll
    for (int ct = 0; ct < 4; ++ct) {
        const int d = ct * 16 + ln;
        #pragma unroll
        for (int reg = 0; reg < 4; ++reg) {
            const int ig = i0 + r0 + qd * 4 + reg;
            const float sv = Sv[((size_t)bh * SS + ig) * DD + d];
            const float o = accpv[ct][reg] - lse[reg] * tot[ct] - 1e9f * sv;
            out[((size_t)(b * SS + ig)) * EE + h * DD + d] = o;
        }
    }
}

// ---------------------------------------------------------------------------
extern "C" void kernel_launch(void* const* d_in, const int* in_sizes, int n_in,
                              void* d_out, int out_size, void* d_ws, size_t ws_size,
                              hipStream_t stream)
{
    const float* query = (const float*)d_in[0];
    const float* key_  = (const float*)d_in[1];
    const float* value = (const float*)d_in[2];
    const float* Wq = (const float*)d_in[3];
    const float* bq = (const float*)d_in[4];
    const float* Wk = (const float*)d_in[5];
    const float* bk = (const float*)d_in[6];
    const float* Wv = (const float*)d_in[7];
    const float* bv = (const float*)d_in[8];
    const float* pb = (const float*)d_in[9];
    float* out = (float*)d_out;

    float* ws = (float*)d_ws;
    const size_t SZ = (size_t)BB * SS * EE;          // 4M elements
    float* Svb  = ws;                                 // fp32 Sv [bh][s][d]
    float* Totb = ws + SZ;                            // 2048
    float* segs = Totb + (size_t)BB * HH * DD;        // 32*64*32 = 65536
    ushort_t* us  = (ushort_t*)(segs + (size_t)BB * HH * DD * 32);
    ushort_t* qbp = us;                               // bf16 q  [bh][s][d] swz
    ushort_t* kbp = qbp + SZ;                         // bf16 k  [bh][s][d] swz
    ushort_t* vtp = kbp + SZ;                         // bf16 vt [bh][d][s] swz
    ushort_t* Xbf = vtp + SZ;                         // 3 x (B*S x E)
    ushort_t* Wbf = Xbf + 3 * SZ;                     // 3 x (E x E)

    const int ngroups = (3 * BB * SS + 3 * EE) * (EE / 8);
    repack_all<<<ngroups / 256, 256, 0, stream>>>(query, key_, value, Wq, Wk, Wv, Xbf, Wbf);

    proj_kernel<<<dim3(BB * SS / 128, EE / 128, 3), 256, 0, stream>>>(
        Xbf, Wbf, bq, bk, bv, qbp, kbp, vtp);

    scan_chunks<<<dim3(8, BB * HH), 256, 0, stream>>>(vtp, segs);
    scan_finalize<<<dim3(32, BB * HH), 256, 0, stream>>>(vtp, segs, Svb, Totb);

    attn_kernel<<<BB * HH * (SS / 128), 512, 0, stream>>>(
        qbp, kbp, vtp, Svb, Totb, pb, out);
}

// Round 5
// 258.918 us; speedup vs baseline: 1.0049x; 1.0049x over previous
//
#include <hip/hip_runtime.h>
#include <math.h>

constexpr int BB = 2;
constexpr int SS = 2048;
constexpr int EE = 1024;
constexpr int HH = 16;
constexpr int DD = 64;

typedef short short8 __attribute__((ext_vector_type(8)));
typedef short short4_t __attribute__((ext_vector_type(4)));
typedef float floatx4 __attribute__((ext_vector_type(4)));
typedef unsigned short ushort_t;

__device__ __forceinline__ ushort_t f2bf(float f) {
    unsigned int u = __float_as_uint(f);
    u += 0x7fffu + ((u >> 16) & 1u);   // RNE
    return (ushort_t)(u >> 16);
}
__device__ __forceinline__ float bf2f(short s) {
    return __uint_as_float(((unsigned)(ushort_t)s) << 16);
}

// async global->LDS, 16 B per lane; LDS dest = wave-uniform base + lane*16
__device__ __forceinline__ void gl_lds16(const void* g, void* l) {
    __builtin_amdgcn_global_load_lds(
        (const __attribute__((address_space(1))) void*)g,
        (__attribute__((address_space(3))) void*)l, 16, 0, 0);
}

// ---------------------------------------------------------------------------
// fp32 -> bf16 repack with XOR-group swizzle (phys group = g ^ (row&7) within
// each 64-col block). All 3 X inputs and all 3 W matrices in one grid.
// ---------------------------------------------------------------------------
__global__ __launch_bounds__(256) void repack_all(
    const float* __restrict__ x0, const float* __restrict__ x1, const float* __restrict__ x2,
    const float* __restrict__ w0, const float* __restrict__ w1, const float* __restrict__ w2,
    ushort_t* __restrict__ Xbf, ushort_t* __restrict__ Wbf)
{
    const int idx = blockIdx.x * 256 + threadIdx.x;   // group-of-8 id
    const int row = idx >> 7;                          // 128 groups per row
    const int gir = idx & 127;
    const float* src;
    ushort_t* dst;
    int r;
    if (row < 3 * BB * SS) {
        const int z = row >> 12; r = row & (BB * SS - 1);
        src = (z == 0) ? x0 : (z == 1) ? x1 : x2;
        dst = Xbf + (size_t)z * BB * SS * EE;
    } else {
        const int rw = row - 3 * BB * SS;
        const int z = rw >> 10; r = rw & (EE - 1);
        src = (z == 0) ? w0 : (z == 1) ? w1 : w2;
        dst = Wbf + (size_t)z * EE * EE;
    }
    const int blk = gir >> 3, g = gir & 7;
    const int gp = g ^ (r & 7);
    const float* sp = src + (size_t)r * EE + gir * 8;
    float4 a = *(const float4*)sp;
    float4 b = *(const float4*)(sp + 4);
    short8 o;
    o[0] = (short)f2bf(a.x); o[1] = (short)f2bf(a.y); o[2] = (short)f2bf(a.z); o[3] = (short)f2bf(a.w);
    o[4] = (short)f2bf(b.x); o[5] = (short)f2bf(b.y); o[6] = (short)f2bf(b.z); o[7] = (short)f2bf(b.w);
    *(short8*)&dst[(size_t)r * EE + blk * 64 + gp * 8] = o;
}

// ---------------------------------------------------------------------------
// bf16 projection GEMM: 128x128 tile, BK=64, global_load_lds staging.
// z=0/1: q/k -> [bh][s][d] bf16 swizzled;  z=2: vt -> [bh][d][s] bf16 swizzled
// ---------------------------------------------------------------------------
__global__ __launch_bounds__(256) void proj_kernel(
    const ushort_t* __restrict__ Xall, const ushort_t* __restrict__ Wall,
    const float* __restrict__ bq, const float* __restrict__ bk, const float* __restrict__ bv,
    ushort_t* __restrict__ qb, ushort_t* __restrict__ kbb, ushort_t* __restrict__ vtb)
{
    __shared__ __align__(16) ushort_t Xs[128 * 64];
    __shared__ __align__(16) ushort_t Ws[128 * 64];

    const int z = blockIdx.z;
    const ushort_t* X = Xall + (size_t)z * BB * SS * EE;
    const ushort_t* W = Wall + (size_t)z * EE * EE;
    const float* bias = (z == 0) ? bq : (z == 1) ? bk : bv;

    const int t = threadIdx.x, w = t >> 6, l = t & 63, ln = t & 15, qd = (t >> 4) & 3;
    const int row0 = blockIdx.x * 128;
    const int col0 = blockIdx.y * 128;
    const int wzm = (w & 1) * 64, wzn = (w >> 1) * 64;

    floatx4 acc[4][4];
    #pragma unroll
    for (int i = 0; i < 4; ++i)
        #pragma unroll
        for (int j = 0; j < 4; ++j)
            acc[i][j] = (floatx4){0.f, 0.f, 0.f, 0.f};

    for (int k0 = 0; k0 < EE; k0 += 64) {
        __syncthreads();
        #pragma unroll
        for (int j = 0; j < 4; ++j) {
            const int c = w * 4 + j;
            const int r = c * 8 + (l >> 3);
            gl_lds16(&X[(size_t)(row0 + r) * EE + k0 + (l & 7) * 8], &Xs[c * 512]);
            gl_lds16(&W[(size_t)(col0 + r) * EE + k0 + (l & 7) * 8], &Ws[c * 512]);
        }
        __syncthreads();

        const ushort_t* Am = (z < 2) ? Ws : Xs;
        const ushort_t* Bn = (z < 2) ? Xs : Ws;
        #pragma unroll
        for (int kh = 0; kh < 2; ++kh) {
            const int sw = ((kh * 4 + qd) ^ (ln & 7)) * 8;
            short8 af[4], bfr[4];
            #pragma unroll
            for (int mi = 0; mi < 4; ++mi)
                af[mi] = *(const short8*)&Am[(wzm + mi * 16 + ln) * 64 + sw];
            #pragma unroll
            for (int ni = 0; ni < 4; ++ni)
                bfr[ni] = *(const short8*)&Bn[(wzn + ni * 16 + ln) * 64 + sw];
            #pragma unroll
            for (int mi = 0; mi < 4; ++mi)
                #pragma unroll
                for (int ni = 0; ni < 4; ++ni)
                    acc[mi][ni] = __builtin_amdgcn_mfma_f32_16x16x32_bf16(af[mi], bfr[ni], acc[mi][ni], 0, 0, 0);
        }
    }

    if (z < 2) {
        ushort_t* dst = z ? kbb : qb;
        #pragma unroll
        for (int mi = 0; mi < 4; ++mi) {
            const int o0 = col0 + wzm + mi * 16 + qd * 4;
            const float4 b4 = *(const float4*)&bias[o0];
            const int h = o0 >> 6, d0 = o0 & 63;
            const int g = d0 >> 3, dlow = d0 & 7;
            #pragma unroll
            for (int ni = 0; ni < 4; ++ni) {
                const int s = row0 + wzn + ni * 16 + ln;
                const int b = s >> 11, sr = s & (SS - 1);
                const int gp = g ^ (sr & 7);
                short4_t pk;
                pk[0] = (short)f2bf(acc[mi][ni][0] + b4.x);
                pk[1] = (short)f2bf(acc[mi][ni][1] + b4.y);
                pk[2] = (short)f2bf(acc[mi][ni][2] + b4.z);
                pk[3] = (short)f2bf(acc[mi][ni][3] + b4.w);
                *(short4_t*)&dst[((size_t)((b * HH + h) * SS) + sr) * DD + gp * 8 + dlow] = pk;
            }
        }
    } else {
        #pragma unroll
        for (int mi = 0; mi < 4; ++mi) {
            const int s0 = row0 + wzm + mi * 16 + qd * 4;
            const int b = s0 >> 11, sr0 = s0 & (SS - 1);
            const int sg = (sr0 >> 3) & 7, slow = sr0 & 7;
            #pragma unroll
            for (int ni = 0; ni < 4; ++ni) {
                const int o = col0 + wzn + ni * 16 + ln;
                const int h = o >> 6, d = o & 63;
                const float bvv = bias[o];
                const int gp2 = sg ^ (d & 7);
                short4_t pk;
                pk[0] = (short)f2bf(acc[mi][ni][0] + bvv);
                pk[1] = (short)f2bf(acc[mi][ni][1] + bvv);
                pk[2] = (short)f2bf(acc[mi][ni][2] + bvv);
                pk[3] = (short)f2bf(acc[mi][ni][3] + bvv);
                *(short4_t*)&vtb[((size_t)((b * HH + h) * DD) + d) * SS + (sr0 & ~63) + gp2 * 8 + slow] = pk;
            }
        }
    }
}

// ---------------------------------------------------------------------------
// 64-s chunk sums of V from bf16 vt[bh][d][s] (swizzle is within-chunk: sum ok)
// segs layout: [bh][c][d]
// ---------------------------------------------------------------------------
__global__ __launch_bounds__(256) void scan_chunks(
    const ushort_t* __restrict__ vtb, float* __restrict__ segs)
{
    const int t = threadIdx.x;
    const int d = blockIdx.x * 8 + (t >> 5);
    const int ch = t & 31;
    const int bh = blockIdx.y;
    const ushort_t* src = vtb + ((size_t)(bh * DD + d)) * SS + ch * 64;
    float s = 0.f;
    #pragma unroll
    for (int i = 0; i < 8; ++i) {
        short8 v = *(const short8*)&src[i * 8];
        #pragma unroll
        for (int j = 0; j < 8; ++j) s += bf2f(v[j]);
    }
    segs[((size_t)bh * 32 + ch) * 64 + d] = s;
}

// ---------------------------------------------------------------------------
// MFMA causal attention, log-softmax decomposition, P kept in registers:
//   St = K·Q^T (16x16x32) -> C-layout == A-layout of 16x16x16 -> PV directly.
//   Sv folded in: within-chunk suffix = U·V MFMA (U = ones where k>i) on the
//   wave's own diagonal tile; beyond-chunk tail from segs chunk sums.
//   out[i,d] = PVraw - lse_i*Tot[d] - 1e9*(Usum[i,d] + tail[d])
// 512 threads = 8 waves x 16 q-rows; 64-wide K tiles, double-buffered staging.
// ---------------------------------------------------------------------------
__global__ __launch_bounds__(512, 4) void attn_kernel(
    const ushort_t* __restrict__ qb, const ushort_t* __restrict__ kbb,
    const ushort_t* __restrict__ vtb, const float* __restrict__ segs,
    const float* __restrict__ pb, float* __restrict__ out)
{
    __shared__ __align__(16) ushort_t Ks[2][64 * 64];   // [k][d], swizzled by k&7
    __shared__ __align__(16) ushort_t Vt[2][64 * 64];   // [d][k], swizzled by d&7
    __shared__ float pbL[2048];                          // pb[h][rel], rel=i-k>=0
    __shared__ __align__(16) float segsL[32 * 64];       // [c][d] chunk sums

    const int t = threadIdx.x, w = t >> 6, ln = t & 15, qd = (t >> 4) & 3;
    const int id = blockIdx.x, bh = id & 31, tt = id >> 5;
    const int qt = (tt < 8) ? (15 - tt) : (tt - 8);   // heavy-first pairing
    const int b = bh >> 4, h = bh & 15, i0 = qt * 128;
    const int r0 = 16 * w;

    {   // pos_bias slice (rel 0..2047); base is only 4B-aligned -> scalar loads
        const float* p = pb + h * (2 * SS - 1) + (SS - 1);
        #pragma unroll
        for (int j = 0; j < 4; ++j) pbL[t * 4 + j] = p[t * 4 + j];
    }
    // chunk sums -> LDS (async; drained by the first barrier)
    gl_lds16(&segs[((size_t)bh * 32) * 64 + t * 4], &segsL[w * 256]);

    // Q fragments (B-operand of St): q-row = i0 + r0 + ln
    short8 qf[2];
    #pragma unroll
    for (int kh = 0; kh < 2; ++kh)
        qf[kh] = *(const short8*)&qb[((size_t)bh * SS + i0 + r0 + ln) * DD + (((kh * 4 + qd) ^ (ln & 7)) * 8)];

    floatx4 accpv[4], accsv[4];
    #pragma unroll
    for (int ct = 0; ct < 4; ++ct) {
        accpv[ct] = (floatx4){0.f, 0.f, 0.f, 0.f};
        accsv[ct] = (floatx4){0.f, 0.f, 0.f, 0.f};
    }
    float psum = 0.f;

    const int nkt = 2 * qt + 2;
    const int ownkt = 2 * qt + (w >> 2);      // tile holding this wave's own chunk
    const int iloc = (w & 3) * 16 + ln;       // q-row within own 64-chunk

    auto stage = [&](int buf, int kt) {
        const int k0 = kt * 64;
        const int row = t >> 3, cg = t & 7;    // 64 rows x 8 groups
        gl_lds16(&kbb[((size_t)bh * SS + k0 + row) * DD + cg * 8], &Ks[buf][w * 512]);
        gl_lds16(&vtb[((size_t)bh * DD + row) * SS + k0 + cg * 8], &Vt[buf][w * 512]);
    };

    stage(0, 0);
    for (int kt = 0; kt < nkt; ++kt) {
        __syncthreads();                                  // drains prefetch
        if (kt + 1 < nkt) stage((kt + 1) & 1, kt + 1);    // issue next prefetch
        const int k0 = kt * 64, kdiag = i0 - k0;
        if (kdiag + r0 + 15 < 0) continue;                // fully masked for wave
        const ushort_t* KsC = Ks[kt & 1];
        const ushort_t* VtC = Vt[kt & 1];

        // St = K·Q^T: A = K rows (m=k), B = Q rows (n=q). 4 m-tiles x 2 kh.
        floatx4 aq[4];
        #pragma unroll
        for (int mt = 0; mt < 4; ++mt) aq[mt] = (floatx4){0.f, 0.f, 0.f, 0.f};
        #pragma unroll
        for (int kh = 0; kh < 2; ++kh) {
            const int sw = ((kh * 4 + qd) ^ (ln & 7)) * 8;
            #pragma unroll
            for (int mt = 0; mt < 4; ++mt) {
                short8 af = *(const short8*)&KsC[(mt * 16 + ln) * 64 + sw];
                aq[mt] = __builtin_amdgcn_mfma_f32_16x16x32_bf16(af, qf[kh], aq[mt], 0, 0, 0);
            }
        }

        // softmax terms in registers; P-frags (A of 16x16x16) built in-place.
        // lane holds q = ln, k = k0 + mt*16 + qd*4 + reg
        short4_t pfrag[4];
        const bool full = (kdiag + r0 >= 63);   // max k <= min i for this wave
        #pragma unroll
        for (int mt = 0; mt < 4; ++mt) {
            const int base = kdiag + r0 + ln - mt * 16 - qd * 4;   // rel for reg=0
            #pragma unroll
            for (int reg = 0; reg < 4; ++reg) {
                if (full) {
                    const float val = aq[mt][reg] * 0.125f + pbL[base - reg];
                    psum += __expf(val);
                    pfrag[mt][reg] = (short)f2bf(val);
                } else {
                    const int rel = base - reg;
                    const bool ok = rel >= 0;
                    const float val = aq[mt][reg] * 0.125f + pbL[ok ? rel : 0];
                    psum += ok ? __expf(val) : 0.f;
                    pfrag[mt][reg] = ok ? (short)f2bf(val) : (short)0;
                }
            }
        }

        // PV (and U·V for Sv on the wave's own diagonal tile)
        const bool own = (kt == ownkt);
        #pragma unroll
        for (int kk = 0; kk < 4; ++kk) {
            short4_t uf;
            if (own) {
                #pragma unroll
                for (int j = 0; j < 4; ++j)
                    uf[j] = (kk * 16 + qd * 4 + j > iloc) ? (short)0x3F80 : (short)0;
            }
            #pragma unroll
            for (int ct = 0; ct < 4; ++ct) {
                const int off = (ct * 16 + ln) * 64 + (((kk * 2 + (qd >> 1)) ^ (ln & 7)) * 8 + (qd & 1) * 4);
                short4_t bfr = *(const short4_t*)&VtC[off];
                accpv[ct] = __builtin_amdgcn_mfma_f32_16x16x16bf16_1k(pfrag[kk], bfr, accpv[ct], 0, 0, 0);
                if (own)
                    accsv[ct] = __builtin_amdgcn_mfma_f32_16x16x16bf16_1k(uf, bfr, accsv[ct], 0, 0, 0);
            }
        }
    }

    // row-sum of exp over k: reduce across the 4 quads (same q = ln)
    float p = psum;
    p += __shfl_xor(p, 16, 64);
    p += __shfl_xor(p, 32, 64);
    const float lseq = __logf(p);            // lse for q-row = ln
    float lseR[4];
    #pragma unroll
    for (int reg = 0; reg < 4; ++reg)
        lseR[reg] = __shfl(lseq, qd * 4 + reg, 64);   // lse for C-layout row

    // Tot[d] and beyond-chunk tail[d] from chunk sums
    const int cmin = 2 * qt + (w >> 2) + 1;
    float tot[4], tail[4];
    #pragma unroll
    for (int ct = 0; ct < 4; ++ct) {
        float T = 0.f, L = 0.f;
        for (int c = 0; c < 32; ++c) {
            const float s = segsL[c * 64 + ct * 16 + ln];
            T += s;
            if (c >= cmin) L += s;
        }
        tot[ct] = T; tail[ct] = L;
    }

    #pragma unroll
    for (int ct = 0; ct < 4; ++ct) {
        const int d = ct * 16 + ln;
        #pragma unroll
        for (int reg = 0; reg < 4; ++reg) {
            const int ig = i0 + r0 + qd * 4 + reg;
            const float o = accpv[ct][reg] - lseR[reg] * tot[ct]
                          - 1e9f * (accsv[ct][reg] + tail[ct]);
            out[((size_t)(b * SS + ig)) * EE + h * DD + d] = o;
        }
    }
}

// ---------------------------------------------------------------------------
extern "C" void kernel_launch(void* const* d_in, const int* in_sizes, int n_in,
                              void* d_out, int out_size, void* d_ws, size_t ws_size,
                              hipStream_t stream)
{
    const float* query = (const float*)d_in[0];
    const float* key_  = (const float*)d_in[1];
    const float* value = (const float*)d_in[2];
    const float* Wq = (const float*)d_in[3];
    const float* bq = (const float*)d_in[4];
    const float* Wk = (const float*)d_in[5];
    const float* bk = (const float*)d_in[6];
    const float* Wv = (const float*)d_in[7];
    const float* bv = (const float*)d_in[8];
    const float* pb = (const float*)d_in[9];
    float* out = (float*)d_out;

    float* ws = (float*)d_ws;
    const size_t SZ = (size_t)BB * SS * EE;          // 4M elements
    float* segs = ws;                                 // 32 bh x 32 c x 64 d
    ushort_t* us  = (ushort_t*)(segs + (size_t)BB * HH * 32 * DD);
    ushort_t* qbp = us;                               // bf16 q  [bh][s][d] swz
    ushort_t* kbp = qbp + SZ;                         // bf16 k  [bh][s][d] swz
    ushort_t* vtp = kbp + SZ;                         // bf16 vt [bh][d][s] swz
    ushort_t* Xbf = vtp + SZ;                         // 3 x (B*S x E)
    ushort_t* Wbf = Xbf + 3 * SZ;                     // 3 x (E x E)

    const int ngroups = (3 * BB * SS + 3 * EE) * (EE / 8);
    repack_all<<<ngroups / 256, 256, 0, stream>>>(query, key_, value, Wq, Wk, Wv, Xbf, Wbf);

    proj_kernel<<<dim3(BB * SS / 128, EE / 128, 3), 256, 0, stream>>>(
        Xbf, Wbf, bq, bk, bv, qbp, kbp, vtp);

    scan_chunks<<<dim3(8, BB * HH), 256, 0, stream>>>(vtp, segs);

    attn_kernel<<<BB * HH * (SS / 128), 512, 0, stream>>>(
        qbp, kbp, vtp, segs, pb, out);
}

// Round 8
// 256.615 us; speedup vs baseline: 1.0139x; 1.0090x over previous
//
#include <hip/hip_runtime.h>
#include <math.h>

constexpr int BB = 2;
constexpr int SS = 2048;
constexpr int EE = 1024;
constexpr int HH = 16;
constexpr int DD = 64;

typedef short short8 __attribute__((ext_vector_type(8)));
typedef short short4_t __attribute__((ext_vector_type(4)));
typedef float floatx4 __attribute__((ext_vector_type(4)));
typedef unsigned short ushort_t;

__device__ __forceinline__ ushort_t f2bf(float f) {
    unsigned int u = __float_as_uint(f);
    u += 0x7fffu + ((u >> 16) & 1u);   // RNE
    return (ushort_t)(u >> 16);
}
__device__ __forceinline__ float bf2f(short s) {
    return __uint_as_float(((unsigned)(ushort_t)s) << 16);
}

// async global->LDS, 16 B per lane; LDS dest = wave-uniform base + lane*16
__device__ __forceinline__ void gl_lds16(const void* g, void* l) {
    __builtin_amdgcn_global_load_lds(
        (const __attribute__((address_space(1))) void*)g,
        (__attribute__((address_space(3))) void*)l, 16, 0, 0);
}

// ---------------------------------------------------------------------------
// fp32 -> bf16 repack with XOR-group swizzle (phys group = g ^ (row&7) within
// each 64-col block). All 3 X inputs and all 3 W matrices in one grid.
// [component verbatim from R4 — passed]
// ---------------------------------------------------------------------------
__global__ __launch_bounds__(256) void repack_all(
    const float* __restrict__ x0, const float* __restrict__ x1, const float* __restrict__ x2,
    const float* __restrict__ w0, const float* __restrict__ w1, const float* __restrict__ w2,
    ushort_t* __restrict__ Xbf, ushort_t* __restrict__ Wbf)
{
    const int idx = blockIdx.x * 256 + threadIdx.x;   // group-of-8 id
    const int row = idx >> 7;                          // 128 groups per row
    const int gir = idx & 127;
    const float* src;
    ushort_t* dst;
    int r;
    if (row < 3 * BB * SS) {
        const int z = row >> 12; r = row & (BB * SS - 1);
        src = (z == 0) ? x0 : (z == 1) ? x1 : x2;
        dst = Xbf + (size_t)z * BB * SS * EE;
    } else {
        const int rw = row - 3 * BB * SS;
        const int z = rw >> 10; r = rw & (EE - 1);
        src = (z == 0) ? w0 : (z == 1) ? w1 : w2;
        dst = Wbf + (size_t)z * EE * EE;
    }
    const int blk = gir >> 3, g = gir & 7;
    const int gp = g ^ (r & 7);
    const float* sp = src + (size_t)r * EE + gir * 8;
    float4 a = *(const float4*)sp;
    float4 b = *(const float4*)(sp + 4);
    short8 o;
    o[0] = (short)f2bf(a.x); o[1] = (short)f2bf(a.y); o[2] = (short)f2bf(a.z); o[3] = (short)f2bf(a.w);
    o[4] = (short)f2bf(b.x); o[5] = (short)f2bf(b.y); o[6] = (short)f2bf(b.z); o[7] = (short)f2bf(b.w);
    *(short8*)&dst[(size_t)r * EE + blk * 64 + gp * 8] = o;
}

// ---------------------------------------------------------------------------
// bf16 projection GEMM: 128x128 tile, BK=64, global_load_lds staging.
// z=0/1: q/k -> [bh][s][d] bf16 swizzled;  z=2: vt -> [bh][d][s] bf16 swizzled
// [component verbatim from R4 — passed]
// ---------------------------------------------------------------------------
__global__ __launch_bounds__(256) void proj_kernel(
    const ushort_t* __restrict__ Xall, const ushort_t* __restrict__ Wall,
    const float* __restrict__ bq, const float* __restrict__ bk, const float* __restrict__ bv,
    ushort_t* __restrict__ qb, ushort_t* __restrict__ kbb, ushort_t* __restrict__ vtb)
{
    __shared__ __align__(16) ushort_t Xs[128 * 64];
    __shared__ __align__(16) ushort_t Ws[128 * 64];

    const int z = blockIdx.z;
    const ushort_t* X = Xall + (size_t)z * BB * SS * EE;
    const ushort_t* W = Wall + (size_t)z * EE * EE;
    const float* bias = (z == 0) ? bq : (z == 1) ? bk : bv;

    const int t = threadIdx.x, w = t >> 6, l = t & 63, ln = t & 15, qd = (t >> 4) & 3;
    const int row0 = blockIdx.x * 128;
    const int col0 = blockIdx.y * 128;
    const int wzm = (w & 1) * 64, wzn = (w >> 1) * 64;

    floatx4 acc[4][4];
    #pragma unroll
    for (int i = 0; i < 4; ++i)
        #pragma unroll
        for (int j = 0; j < 4; ++j)
            acc[i][j] = (floatx4){0.f, 0.f, 0.f, 0.f};

    for (int k0 = 0; k0 < EE; k0 += 64) {
        __syncthreads();
        #pragma unroll
        for (int j = 0; j < 4; ++j) {
            const int c = w * 4 + j;
            const int r = c * 8 + (l >> 3);
            gl_lds16(&X[(size_t)(row0 + r) * EE + k0 + (l & 7) * 8], &Xs[c * 512]);
            gl_lds16(&W[(size_t)(col0 + r) * EE + k0 + (l & 7) * 8], &Ws[c * 512]);
        }
        __syncthreads();

        const ushort_t* Am = (z < 2) ? Ws : Xs;
        const ushort_t* Bn = (z < 2) ? Xs : Ws;
        #pragma unroll
        for (int kh = 0; kh < 2; ++kh) {
            const int sw = ((kh * 4 + qd) ^ (ln & 7)) * 8;
            short8 af[4], bfr[4];
            #pragma unroll
            for (int mi = 0; mi < 4; ++mi)
                af[mi] = *(const short8*)&Am[(wzm + mi * 16 + ln) * 64 + sw];
            #pragma unroll
            for (int ni = 0; ni < 4; ++ni)
                bfr[ni] = *(const short8*)&Bn[(wzn + ni * 16 + ln) * 64 + sw];
            #pragma unroll
            for (int mi = 0; mi < 4; ++mi)
                #pragma unroll
                for (int ni = 0; ni < 4; ++ni)
                    acc[mi][ni] = __builtin_amdgcn_mfma_f32_16x16x32_bf16(af[mi], bfr[ni], acc[mi][ni], 0, 0, 0);
        }
    }

    if (z < 2) {
        ushort_t* dst = z ? kbb : qb;
        #pragma unroll
        for (int mi = 0; mi < 4; ++mi) {
            const int o0 = col0 + wzm + mi * 16 + qd * 4;
            const float4 b4 = *(const float4*)&bias[o0];
            const int h = o0 >> 6, d0 = o0 & 63;
            const int g = d0 >> 3, dlow = d0 & 7;
            #pragma unroll
            for (int ni = 0; ni < 4; ++ni) {
                const int s = row0 + wzn + ni * 16 + ln;
                const int b = s >> 11, sr = s & (SS - 1);
                const int gp = g ^ (sr & 7);
                short4_t pk;
                pk[0] = (short)f2bf(acc[mi][ni][0] + b4.x);
                pk[1] = (short)f2bf(acc[mi][ni][1] + b4.y);
                pk[2] = (short)f2bf(acc[mi][ni][2] + b4.z);
                pk[3] = (short)f2bf(acc[mi][ni][3] + b4.w);
                *(short4_t*)&dst[((size_t)((b * HH + h) * SS) + sr) * DD + gp * 8 + dlow] = pk;
            }
        }
    } else {
        #pragma unroll
        for (int mi = 0; mi < 4; ++mi) {
            const int s0 = row0 + wzm + mi * 16 + qd * 4;
            const int b = s0 >> 11, sr0 = s0 & (SS - 1);
            const int sg = (sr0 >> 3) & 7, slow = sr0 & 7;
            #pragma unroll
            for (int ni = 0; ni < 4; ++ni) {
                const int o = col0 + wzn + ni * 16 + ln;
                const int h = o >> 6, d = o & 63;
                const float bvv = bias[o];
                const int gp2 = sg ^ (d & 7);
                short4_t pk;
                pk[0] = (short)f2bf(acc[mi][ni][0] + bvv);
                pk[1] = (short)f2bf(acc[mi][ni][1] + bvv);
                pk[2] = (short)f2bf(acc[mi][ni][2] + bvv);
                pk[3] = (short)f2bf(acc[mi][ni][3] + bvv);
                *(short4_t*)&vtb[((size_t)((b * HH + h) * DD) + d) * SS + (sr0 & ~63) + gp2 * 8 + slow] = pk;
            }
        }
    }
}

// ---------------------------------------------------------------------------
// 64-s chunk SUFFIX sums of V from bf16 vt[bh][d][s]:
// segsuf[bh][c][d] = sum over chunks c' >= c, c in [0,32] (row 32 = 0).
// Swizzle permutes within a 64-chunk only -> chunk sums invariant.
// ---------------------------------------------------------------------------
__global__ __launch_bounds__(256) void scan_chunks(
    const ushort_t* __restrict__ vtb, float* __restrict__ segsuf)
{
    const int t = threadIdx.x;
    const int d = blockIdx.x * 8 + (t >> 5);
    const int ch = t & 31;
    const int bh = blockIdx.y;
    const ushort_t* src = vtb + ((size_t)(bh * DD + d)) * SS + ch * 64;
    float s = 0.f;
    #pragma unroll
    for (int i = 0; i < 8; ++i) {
        short8 v = *(const short8*)&src[i * 8];
        #pragma unroll
        for (int j = 0; j < 8; ++j) s += bf2f(v[j]);
    }
    // inclusive suffix scan across the 32 lanes sharing d (width-32 groups)
    #pragma unroll
    for (int delta = 1; delta < 32; delta <<= 1) {
        const float v = __shfl_down(s, delta, 32);
        if (ch + delta < 32) s += v;
    }
    segsuf[((size_t)bh * 33 + ch) * 64 + d] = s;
    if (ch == 31) segsuf[((size_t)bh * 33 + 32) * 64 + d] = 0.f;
}

// ---------------------------------------------------------------------------
// MFMA causal attention, log-softmax decomposition, P kept in registers.
// [attn verbatim from R5 (passed); ONLY the epilogue tot/tail source changed:
//  segsL (8KB LDS stage + 32-iter loops) -> two direct global reads of the
//  suffix-sum table. LDS 49152 -> 40960 B.]
//   St = K·Q^T (16x16x32) -> C-layout == A-layout of 16x16x16 -> PV directly.
//   Sv folded in: within-chunk suffix = U·V MFMA on the wave's own diagonal
//   tile; beyond-chunk tail + Tot from segsuf.
//   out[i,d] = PVraw - lse_i*Tot[d] - 1e9*(Usum[i,d] + tail[d])
// ---------------------------------------------------------------------------
__global__ __launch_bounds__(512, 4) void attn_kernel(
    const ushort_t* __restrict__ qb, const ushort_t* __restrict__ kbb,
    const ushort_t* __restrict__ vtb, const float* __restrict__ segsuf,
    const float* __restrict__ pb, float* __restrict__ out)
{
    __shared__ __align__(16) ushort_t Ks[2][64 * 64];   // [k][d], swizzled by k&7
    __shared__ __align__(16) ushort_t Vt[2][64 * 64];   // [d][k], swizzled by d&7
    __shared__ float pbL[2048];                          // pb[h][rel], rel=i-k>=0

    const int t = threadIdx.x, w = t >> 6, ln = t & 15, qd = (t >> 4) & 3;
    const int id = blockIdx.x, bh = id & 31, tt = id >> 5;
    const int qt = (tt < 8) ? (15 - tt) : (tt - 8);   // heavy-first pairing
    const int b = bh >> 4, h = bh & 15, i0 = qt * 128;
    const int r0 = 16 * w;

    {   // pos_bias slice (rel 0..2047); base only 4B-aligned -> scalar loads
        const float* p = pb + h * (2 * SS - 1) + (SS - 1);
        #pragma unroll
        for (int j = 0; j < 4; ++j) pbL[t * 4 + j] = p[t * 4 + j];
    }

    // Q fragments (B-operand of St): q-row = i0 + r0 + ln
    short8 qf[2];
    #pragma unroll
    for (int kh = 0; kh < 2; ++kh)
        qf[kh] = *(const short8*)&qb[((size_t)bh * SS + i0 + r0 + ln) * DD + (((kh * 4 + qd) ^ (ln & 7)) * 8)];

    floatx4 accpv[4], accsv[4];
    #pragma unroll
    for (int ct = 0; ct < 4; ++ct) {
        accpv[ct] = (floatx4){0.f, 0.f, 0.f, 0.f};
        accsv[ct] = (floatx4){0.f, 0.f, 0.f, 0.f};
    }
    float psum = 0.f;

    const int nkt = 2 * qt + 2;
    const int ownkt = 2 * qt + (w >> 2);      // tile holding this wave's own chunk
    const int iloc = (w & 3) * 16 + ln;       // this lane's q-row within own chunk

    auto stage = [&](int buf, int kt) {
        const int k0 = kt * 64;
        const int row = t >> 3, cg = t & 7;    // 64 rows x 8 groups
        gl_lds16(&kbb[((size_t)bh * SS + k0 + row) * DD + cg * 8], &Ks[buf][w * 512]);
        gl_lds16(&vtb[((size_t)bh * DD + row) * SS + k0 + cg * 8], &Vt[buf][w * 512]);
    };

    stage(0, 0);
    for (int kt = 0; kt < nkt; ++kt) {
        __syncthreads();                                  // drains prefetch
        if (kt + 1 < nkt) stage((kt + 1) & 1, kt + 1);    // issue next prefetch
        const int k0 = kt * 64, kdiag = i0 - k0;
        if (kdiag + r0 + 15 < 0) continue;                // fully masked for wave
        const ushort_t* KsC = Ks[kt & 1];
        const ushort_t* VtC = Vt[kt & 1];

        // St = K·Q^T: A = K rows (m=k), B = Q rows (n=q). 4 m-tiles x 2 kh.
        floatx4 aq[4];
        #pragma unroll
        for (int mt = 0; mt < 4; ++mt) aq[mt] = (floatx4){0.f, 0.f, 0.f, 0.f};
        #pragma unroll
        for (int kh = 0; kh < 2; ++kh) {
            const int sw = ((kh * 4 + qd) ^ (ln & 7)) * 8;
            #pragma unroll
            for (int mt = 0; mt < 4; ++mt) {
                short8 af = *(const short8*)&KsC[(mt * 16 + ln) * 64 + sw];
                aq[mt] = __builtin_amdgcn_mfma_f32_16x16x32_bf16(af, qf[kh], aq[mt], 0, 0, 0);
            }
        }

        // softmax terms in registers; lane holds q = ln, k = k0+mt*16+qd*4+reg
        short4_t pfrag[4];
        const bool full = (kdiag + r0 >= 63);   // max k <= min i for this wave
        #pragma unroll
        for (int mt = 0; mt < 4; ++mt) {
            const int base = kdiag + r0 + ln - mt * 16 - qd * 4;   // rel for reg=0
            #pragma unroll
            for (int reg = 0; reg < 4; ++reg) {
                if (full) {
                    const float val = aq[mt][reg] * 0.125f + pbL[base - reg];
                    psum += __expf(val);
                    pfrag[mt][reg] = (short)f2bf(val);
                } else {
                    const int rel = base - reg;
                    const bool ok = rel >= 0;
                    const float val = aq[mt][reg] * 0.125f + pbL[ok ? rel : 0];
                    psum += ok ? __expf(val) : 0.f;
                    pfrag[mt][reg] = ok ? (short)f2bf(val) : (short)0;
                }
            }
        }

        // PV (and U·V for Sv on the wave's own diagonal tile), x16 MFMA
        const bool own = (kt == ownkt);
        #pragma unroll
        for (int kk = 0; kk < 4; ++kk) {
            short4_t uf;
            if (own) {
                #pragma unroll
                for (int j = 0; j < 4; ++j)
                    uf[j] = (kk * 16 + qd * 4 + j > iloc) ? (short)0x3F80 : (short)0;
            }
            #pragma unroll
            for (int ct = 0; ct < 4; ++ct) {
                const int off = (ct * 16 + ln) * 64 + (((kk * 2 + (qd >> 1)) ^ (ln & 7)) * 8 + (qd & 1) * 4);
                short4_t bfr = *(const short4_t*)&VtC[off];
                accpv[ct] = __builtin_amdgcn_mfma_f32_16x16x16bf16_1k(pfrag[kk], bfr, accpv[ct], 0, 0, 0);
                if (own)
                    accsv[ct] = __builtin_amdgcn_mfma_f32_16x16x16bf16_1k(uf, bfr, accsv[ct], 0, 0, 0);
            }
        }
    }

    // row-sum of exp over k: reduce across the 4 quads (same q = ln)
    float p = psum;
    p += __shfl_xor(p, 16, 64);
    p += __shfl_xor(p, 32, 64);
    const float lseq = __logf(p);            // lse for q-row = ln
    float lseR[4];
    #pragma unroll
    for (int reg = 0; reg < 4; ++reg)
        lseR[reg] = __shfl(lseq, qd * 4 + reg, 64);   // lse for C-layout row

    // Tot[d] and beyond-chunk tail[d]: two direct reads of the suffix table
    const int cmin = 2 * qt + (w >> 2) + 1;
    float tot[4], tail[4];
    #pragma unroll
    for (int ct = 0; ct < 4; ++ct) {
        const int d = ct * 16 + ln;
        tot[ct]  = segsuf[((size_t)bh * 33) * 64 + d];
        tail[ct] = segsuf[((size_t)bh * 33 + cmin) * 64 + d];
    }

    #pragma unroll
    for (int ct = 0; ct < 4; ++ct) {
        const int d = ct * 16 + ln;
        #pragma unroll
        for (int reg = 0; reg < 4; ++reg) {
            const int ig = i0 + r0 + qd * 4 + reg;
            const float o = accpv[ct][reg] - lseR[reg] * tot[ct]
                          - 1e9f * (accsv[ct][reg] + tail[ct]);
            out[((size_t)(b * SS + ig)) * EE + h * DD + d] = o;
        }
    }
}

// ---------------------------------------------------------------------------
extern "C" void kernel_launch(void* const* d_in, const int* in_sizes, int n_in,
                              void* d_out, int out_size, void* d_ws, size_t ws_size,
                              hipStream_t stream)
{
    const float* query = (const float*)d_in[0];
    const float* key_  = (const float*)d_in[1];
    const float* value = (const float*)d_in[2];
    const float* Wq = (const float*)d_in[3];
    const float* bq = (const float*)d_in[4];
    const float* Wk = (const float*)d_in[5];
    const float* bk = (const float*)d_in[6];
    const float* Wv = (const float*)d_in[7];
    const float* bv = (const float*)d_in[8];
    const float* pb = (const float*)d_in[9];
    float* out = (float*)d_out;

    float* ws = (float*)d_ws;
    const size_t SZ = (size_t)BB * SS * EE;          // 4M elements
    float* segsuf = ws;                               // 32 bh x 33 c x 64 d
    ushort_t* us  = (ushort_t*)(segsuf + (size_t)BB * HH * 33 * DD);
    ushort_t* qbp = us;                               // bf16 q  [bh][s][d] swz
    ushort_t* kbp = qbp + SZ;                         // bf16 k  [bh][s][d] swz
    ushort_t* vtp = kbp + SZ;                         // bf16 vt [bh][d][s] swz
    ushort_t* Xbf = vtp + SZ;                         // 3 x (B*S x E)
    ushort_t* Wbf = Xbf + 3 * SZ;                     // 3 x (E x E)

    const int ngroups = (3 * BB * SS + 3 * EE) * (EE / 8);
    repack_all<<<ngroups / 256, 256, 0, stream>>>(query, key_, value, Wq, Wk, Wv, Xbf, Wbf);

    proj_kernel<<<dim3(BB * SS / 128, EE / 128, 3), 256, 0, stream>>>(
        Xbf, Wbf, bq, bk, bv, qbp, kbp, vtp);

    scan_chunks<<<dim3(8, BB * HH), 256, 0, stream>>>(vtp, segsuf);

    attn_kernel<<<BB * HH * (SS / 128), 512, 0, stream>>>(
        qbp, kbp, vtp, segsuf, pb, out);
}